// Round 6
// baseline (87.091 us; speedup 1.0000x reference)
//
#include <hip/hip_runtime.h>
#include <hip/hip_bf16.h>

#define BH 128
#define L 1024
#define D 64
#define MASK_VALUE -1000000.0f
#define KVBLK 64
#define RESCALE_THR 8.0f

typedef __attribute__((ext_vector_type(8))) __bf16 bf16x8;
typedef __attribute__((ext_vector_type(16))) float f32x16;
typedef __attribute__((ext_vector_type(4))) float f32x4;
typedef __attribute__((ext_vector_type(2))) float f32x2;
typedef __attribute__((ext_vector_type(4))) unsigned int u32x4;
typedef __attribute__((ext_vector_type(2))) int i32x2;

__device__ __forceinline__ unsigned cvt_pk(float lo, float hi) {
    unsigned r;
    asm("v_cvt_pk_bf16_f32 %0, %1, %2" : "=v"(r) : "v"(lo), "v"(hi));
    return r;
}

__device__ __forceinline__ float exp2_asm(float x) {
    float r; asm("v_exp_f32 %0, %1" : "=v"(r) : "v"(x)); return r;
}

__device__ __forceinline__ f32x16 mfma32(bf16x8 a, bf16x8 b, f32x16 c) {
    return __builtin_amdgcn_mfma_f32_32x32x16_bf16(a, b, c, 0, 0, 0);
}

// half-cross swap (T12): after call a = {a[0:31], b[0:31]}, b = {a[32:63], b[32:63]}
__device__ __forceinline__ void swap32(unsigned& a, unsigned& b) {
    i32x2 r = __builtin_amdgcn_permlane32_swap((int)a, (int)b, false, false);
    a = (unsigned)r[0];
    b = (unsigned)r[1];
}

// P B-fragment from 8 in-lane P values (one 16-k contraction chunk).
// kappa: lane needs P[k = hi2*8+j]; own regs hold {0-3,8-11}+4*hi2 -> one swap
// per pair-of-words fixes both halves (guide T12 recipe).
__device__ __forceinline__ bf16x8 pack_frag(float a0, float a1, float a2, float a3,
                                            float a4, float a5, float a6, float a7) {
    unsigned x = cvt_pk(a0, a1), y = cvt_pk(a2, a3);
    unsigned u = cvt_pk(a4, a5), v = cvt_pk(a6, a7);
    swap32(x, u);
    swap32(y, v);
    u32x4 w; w[0] = x; w[1] = y; w[2] = u; w[3] = v;
    return __builtin_bit_cast(bf16x8, w);
}

// LDS tile rows are 128 bytes; XOR-swizzle 16B slots by (row&7) to kill
// the stride-128B bank conflict on ds_read_b128 (G4).
__device__ __forceinline__ bf16x8 ldsfrag(const unsigned char* base, int row, int colbytes) {
    const u32x4* p = (const u32x4*)(base + row * 128 + (colbytes ^ ((row & 7) << 4)));
    return __builtin_bit_cast(bf16x8, *p);
}

// NO min-waves bound (R3/R4: forced VGPR caps -> 170-200MB spill traffic, 3x slow).
__global__ __launch_bounds__(256)
void attn_kernel(const float* __restrict__ Q, const float* __restrict__ K,
                 const float* __restrict__ V, const int* __restrict__ vlen,
                 float* __restrict__ Out) {
    __shared__ __align__(16) unsigned char Kl[2][64 * 128];  // [k][d] bf16, swizzled
    __shared__ __align__(16) unsigned char Vl[2][64 * 128];  // V^T: [d][k] bf16, swizzled

    const int tid  = threadIdx.x;
    const int lane = tid & 63;
    const int wid  = tid >> 6;   // 0..3

    // XCD swizzle: all 8 q-tiles of a head on one XCD (bid%8 presumed = XCD)
    const int bid  = blockIdx.x;
    const int xcd  = bid & 7;
    const int grp  = bid >> 3;
    const int head = xcd * 16 + (grp & 15);
    const int qt   = grp >> 4;

    const int valid = vlen[head];
    const int nkt   = (valid == 0) ? (L / KVBLK) : ((valid + KVBLK - 1) >> 6);

    const float* Qh = Q + (size_t)head * L * D;
    const float* Kh = K + (size_t)head * L * D;
    const float* Vh = V + (size_t)head * L * D;
    float*       Oh = Out + (size_t)head * L * D;

    const int ql   = lane & 31;   // q within wave block; A-row; D-col
    const int hi2  = lane >> 5;   // fragment half
    const int qrow = qt * 128 + wid * 32 + ql;

    // ---- Q B-frags (per chain step c): Q[qrow][c*16 + hi2*8 + j], scaled ----
    const float QSCALE = 0.125f * 1.44269504088896f;  // 1/sqrt(64) * log2(e)
    bf16x8 qf[4];
#pragma unroll
    for (int c = 0; c < 4; ++c) {
        const float* qp = Qh + (size_t)qrow * D + c * 16 + hi2 * 8;
        f32x4 a = *(const f32x4*)qp;
        f32x4 b = *(const f32x4*)(qp + 4);
        u32x4 w;
        w[0] = cvt_pk(a[0] * QSCALE, a[1] * QSCALE);
        w[1] = cvt_pk(a[2] * QSCALE, a[3] * QSCALE);
        w[2] = cvt_pk(b[0] * QSCALE, b[1] * QSCALE);
        w[3] = cvt_pk(b[2] * QSCALE, b[3] * QSCALE);
        qf[c] = __builtin_bit_cast(bf16x8, w);
    }

    // ---- staging assignments (256 threads) ----
    const int skr = tid >> 2;          // K row (k), 0..63
    const int skc = (tid & 3) * 16;    // K col base (f32), 16 per thread
    const int svk = (tid & 7) * 8;     // V k base (8 consecutive k)
    const int svd = (tid >> 3) * 2;    // V d pair (d, d+1)

    f32x4 rk[4];
    f32x2 rv[8];

    auto load_regs = [&](int kt) {
        const float* kp = Kh + (size_t)(kt * KVBLK + skr) * D + skc;
#pragma unroll
        for (int j = 0; j < 4; ++j) rk[j] = *(const f32x4*)(kp + 4 * j);
        const float* vp = Vh + (size_t)(kt * KVBLK + svk) * D + svd;
#pragma unroll
        for (int j = 0; j < 8; ++j) rv[j] = *(const f32x2*)(vp + (size_t)j * D);
    };

    auto write_lds = [&](int buf) {
        // K: row-major [k][d], 2x ds_write_b128 (swizzled)
        unsigned char* kb = Kl[buf];
        u32x4 w0, w1;
        w0[0] = cvt_pk(rk[0][0], rk[0][1]); w0[1] = cvt_pk(rk[0][2], rk[0][3]);
        w0[2] = cvt_pk(rk[1][0], rk[1][1]); w0[3] = cvt_pk(rk[1][2], rk[1][3]);
        w1[0] = cvt_pk(rk[2][0], rk[2][1]); w1[1] = cvt_pk(rk[2][2], rk[2][3]);
        w1[2] = cvt_pk(rk[3][0], rk[3][1]); w1[3] = cvt_pk(rk[3][2], rk[3][3]);
        const int sw = (skr & 7) << 4;
        *(u32x4*)(kb + skr * 128 + ((skc * 2) ^ sw))      = w0;
        *(u32x4*)(kb + skr * 128 + ((skc * 2 + 16) ^ sw)) = w1;
        // V^T: thread-local transpose of an 8k x 2d patch -> 2x ds_write_b128
        unsigned char* vb = Vl[buf];
        u32x4 t0, t1;
        t0[0] = cvt_pk(rv[0][0], rv[1][0]); t0[1] = cvt_pk(rv[2][0], rv[3][0]);
        t0[2] = cvt_pk(rv[4][0], rv[5][0]); t0[3] = cvt_pk(rv[6][0], rv[7][0]);
        t1[0] = cvt_pk(rv[0][1], rv[1][1]); t1[1] = cvt_pk(rv[2][1], rv[3][1]);
        t1[2] = cvt_pk(rv[4][1], rv[5][1]); t1[3] = cvt_pk(rv[6][1], rv[7][1]);
        *(u32x4*)(vb + svd * 128       + ((svk * 2) ^ ((svd & 7) << 4)))       = t0;
        *(u32x4*)(vb + (svd + 1) * 128 + ((svk * 2) ^ (((svd + 1) & 7) << 4))) = t1;
    };

    // ---- state: O^T accumulators (2 d-blocks x 16), per-lane m/l for q=ql ----
    f32x16 o0, o1;
#pragma unroll
    for (int r = 0; r < 16; ++r) { o0[r] = 0.f; o1[r] = 0.f; }
    float m_run = -INFINITY;
    float l_run = 0.f;

    load_regs(0);
    write_lds(0);
    __syncthreads();

    for (int kt = 0; kt < nkt; ++kt) {
        const int  cur      = kt & 1;
        const bool has_next = (kt + 1 < nkt);
        if (has_next) load_regs(kt + 1);  // issue early; latency hides under compute

        // ---- S^T = K Q^T: s0 = k 0..31, s1 = k 32..63 (lane: q=ql, k spread) ----
        f32x16 s0, s1;
#pragma unroll
        for (int r = 0; r < 16; ++r) { s0[r] = 0.f; s1[r] = 0.f; }
        __builtin_amdgcn_s_setprio(1);
#pragma unroll
        for (int c = 0; c < 4; ++c) {
            bf16x8 kf = ldsfrag(Kl[cur], ql, c * 32 + hi2 * 16);
            s0 = mfma32(kf, qf[c], s0);
        }
#pragma unroll
        for (int c = 0; c < 4; ++c) {
            bf16x8 kf = ldsfrag(Kl[cur], 32 + ql, c * 32 + hi2 * 16);
            s1 = mfma32(kf, qf[c], s1);
        }
        __builtin_amdgcn_s_setprio(0);

        // ---- key-padding mask: k = kt*64 + ksub*32 + (r&3)+8*(r>>2)+4*hi2 ----
        if ((kt + 1) * KVBLK > valid) {
            const int kb0 = kt * KVBLK + 4 * hi2;
#pragma unroll
            for (int r = 0; r < 16; ++r) {
                const int kl = (r & 3) + 8 * (r >> 2);
                if (kb0 + kl >= valid)      s0[r] = MASK_VALUE;
                if (kb0 + 32 + kl >= valid) s1[r] = MASK_VALUE;
            }
        }

        // ---- row max: in-lane tree over 32 + ONE shuffle (other half in lane^32) ----
        float tm;
        {
            float q0 = fmaxf(fmaxf(s0[0], s0[1]), fmaxf(s0[2], s0[3]));
            float q1 = fmaxf(fmaxf(s0[4], s0[5]), fmaxf(s0[6], s0[7]));
            float q2 = fmaxf(fmaxf(s0[8], s0[9]), fmaxf(s0[10], s0[11]));
            float q3 = fmaxf(fmaxf(s0[12], s0[13]), fmaxf(s0[14], s0[15]));
            float q4 = fmaxf(fmaxf(s1[0], s1[1]), fmaxf(s1[2], s1[3]));
            float q5 = fmaxf(fmaxf(s1[4], s1[5]), fmaxf(s1[6], s1[7]));
            float q6 = fmaxf(fmaxf(s1[8], s1[9]), fmaxf(s1[10], s1[11]));
            float q7 = fmaxf(fmaxf(s1[12], s1[13]), fmaxf(s1[14], s1[15]));
            tm = fmaxf(fmaxf(fmaxf(q0, q1), fmaxf(q2, q3)),
                       fmaxf(fmaxf(q4, q5), fmaxf(q6, q7)));
            tm = fmaxf(tm, __shfl_xor(tm, 32));
        }

        // ---- defer-max (T13): rescale only when max grew past THR (all lane-local) ----
        if (!__all(tm <= m_run + RESCALE_THR)) {
            float mnew  = fmaxf(m_run, tm);
            float alpha = exp2_asm(m_run - mnew);  // first tile: exp2(-inf)=0
            l_run *= alpha;
#pragma unroll
            for (int r = 0; r < 16; ++r) { o0[r] *= alpha; o1[r] *= alpha; }
            m_run = mnew;
        }

        // ---- P = exp2(S - m) in place ----
#pragma unroll
        for (int r = 0; r < 16; ++r) {
            s0[r] = exp2_asm(s0[r] - m_run);
            s1[r] = exp2_asm(s1[r] - m_run);
        }

        // ---- in-lane l partial sum (balanced tree) ----
        float lsum;
        {
            float a0 = (s0[0] + s0[1]) + (s0[2] + s0[3]);
            float a1 = (s0[4] + s0[5]) + (s0[6] + s0[7]);
            float a2 = (s0[8] + s0[9]) + (s0[10] + s0[11]);
            float a3 = (s0[12] + s0[13]) + (s0[14] + s0[15]);
            float a4 = (s1[0] + s1[1]) + (s1[2] + s1[3]);
            float a5 = (s1[4] + s1[5]) + (s1[6] + s1[7]);
            float a6 = (s1[8] + s1[9]) + (s1[10] + s1[11]);
            float a7 = (s1[12] + s1[13]) + (s1[14] + s1[15]);
            lsum = ((a0 + a1) + (a2 + a3)) + ((a4 + a5) + (a6 + a7));
        }

        // ---- pack P into B-frags fully in-register (16 cvt_pk + 8 permlane) ----
        bf16x8 pf0 = pack_frag(s0[0], s0[1], s0[2],  s0[3],  s0[4],  s0[5],  s0[6],  s0[7]);
        bf16x8 pf1 = pack_frag(s0[8], s0[9], s0[10], s0[11], s0[12], s0[13], s0[14], s0[15]);
        bf16x8 pf2 = pack_frag(s1[0], s1[1], s1[2],  s1[3],  s1[4],  s1[5],  s1[6],  s1[7]);
        bf16x8 pf3 = pack_frag(s1[8], s1[9], s1[10], s1[11], s1[12], s1[13], s1[14], s1[15]);

        // ---- O^T += V^T P : A = V^T frag (d rows), B = P frag ----
        __builtin_amdgcn_s_setprio(1);
#pragma unroll
        for (int c = 0; c < 4; ++c) {
            bf16x8 vf = ldsfrag(Vl[cur], ql, c * 32 + hi2 * 16);
            bf16x8 pc = (c == 0) ? pf0 : (c == 1) ? pf1 : (c == 2) ? pf2 : pf3;
            o0 = mfma32(vf, pc, o0);
        }
#pragma unroll
        for (int c = 0; c < 4; ++c) {
            bf16x8 vf = ldsfrag(Vl[cur], 32 + ql, c * 32 + hi2 * 16);
            bf16x8 pc = (c == 0) ? pf0 : (c == 1) ? pf1 : (c == 2) ? pf2 : pf3;
            o1 = mfma32(vf, pc, o1);
        }
        __builtin_amdgcn_s_setprio(0);

        // ---- finish l update (overlaps MFMA drain) ----
        lsum += __shfl_xor(lsum, 32);
        l_run += lsum;

        if (has_next) write_lds((kt + 1) & 1);
        __syncthreads();
    }

    // ---- epilogue: per-lane normalize, store O[qrow][d] (d = db*32+8*g+4*hi2+0..3) ----
    const float linv = 1.0f / l_run;
    float* orow = Oh + (size_t)qrow * D;
#pragma unroll
    for (int g = 0; g < 4; ++g) {
        f32x4 w0, w1;
#pragma unroll
        for (int j = 0; j < 4; ++j) {
            w0[j] = o0[g * 4 + j] * linv;
            w1[j] = o1[g * 4 + j] * linv;
        }
        *(f32x4*)(orow + 8 * g + 4 * hi2)      = w0;
        *(f32x4*)(orow + 32 + 8 * g + 4 * hi2) = w1;
    }
}

extern "C" void kernel_launch(void* const* d_in, const int* in_sizes, int n_in,
                              void* d_out, int out_size, void* d_ws, size_t ws_size,
                              hipStream_t stream) {
    const float* Q    = (const float*)d_in[0];
    const float* K    = (const float*)d_in[1];
    const float* V    = (const float*)d_in[2];
    const int*   vlen = (const int*)d_in[3];
    float*       Out  = (float*)d_out;

    dim3 grid(BH * (L / 128));  // 1024 blocks: 8 q-tiles per head
    attn_kernel<<<grid, 256, 0, stream>>>(Q, K, V, vlen, Out);
}